// Round 3
// baseline (107.559 us; speedup 1.0000x reference)
//
#include <hip/hip_runtime.h>

// ScaledRBFKernel: out[i][j] = outputscale * exp(-2 * ||x1[i] - x2[j]||^2)
// x1: [8192,2] f32, x2: [8192,2] f32, out: [8192,8192] f32 (256 MiB -> write-BW bound)
// LENGTHSCALE = 0.5 -> 1/(2*l^2) = 2.0 (baked in)
// R3: same as R2 but nt-store via clang native vector type (HIP float4 is a
// class -> rejected by __builtin_nontemporal_store).

#define N_ROWS 8192
#define M_COLS 8192

typedef float f32x4 __attribute__((ext_vector_type(4)));

__global__ __launch_bounds__(256) void ScaledRBFKernel_55052890800187_kernel(
    const float2* __restrict__ x1,   // [N,2] as float2
    const float2* __restrict__ x2,   // [M,2] as float2
    const float* __restrict__ oscale,
    float* __restrict__ out)
{
    const int i  = blockIdx.y;                              // row 0..8191
    const int j8 = blockIdx.x * blockDim.x + threadIdx.x;   // col-group of 8: 0..1023

    const float2 a = x1[i];
    const float  s = oscale[0];

    // 8 consecutive x2 points = 4 float4 loads (64 B/lane, L1/L2-resident)
    const f32x4* x2v = reinterpret_cast<const f32x4*>(x2);
    f32x4 p0 = x2v[j8 * 4 + 0];
    f32x4 p1 = x2v[j8 * 4 + 1];
    f32x4 p2 = x2v[j8 * 4 + 2];
    f32x4 p3 = x2v[j8 * 4 + 3];

    f32x4 r0, r1;
    {
        float dx = a.x - p0.x, dy = a.y - p0.y;
        r0.x = s * __expf(-2.0f * (dx * dx + dy * dy));
    }
    {
        float dx = a.x - p0.z, dy = a.y - p0.w;
        r0.y = s * __expf(-2.0f * (dx * dx + dy * dy));
    }
    {
        float dx = a.x - p1.x, dy = a.y - p1.y;
        r0.z = s * __expf(-2.0f * (dx * dx + dy * dy));
    }
    {
        float dx = a.x - p1.z, dy = a.y - p1.w;
        r0.w = s * __expf(-2.0f * (dx * dx + dy * dy));
    }
    {
        float dx = a.x - p2.x, dy = a.y - p2.y;
        r1.x = s * __expf(-2.0f * (dx * dx + dy * dy));
    }
    {
        float dx = a.x - p2.z, dy = a.y - p2.w;
        r1.y = s * __expf(-2.0f * (dx * dx + dy * dy));
    }
    {
        float dx = a.x - p3.x, dy = a.y - p3.y;
        r1.z = s * __expf(-2.0f * (dx * dx + dy * dy));
    }
    {
        float dx = a.x - p3.z, dy = a.y - p3.w;
        r1.w = s * __expf(-2.0f * (dx * dx + dy * dy));
    }

    f32x4* o = reinterpret_cast<f32x4*>(out) + (size_t)i * (M_COLS / 4) + j8 * 2;
    __builtin_nontemporal_store(r0, o + 0);
    __builtin_nontemporal_store(r1, o + 1);
}

extern "C" void kernel_launch(void* const* d_in, const int* in_sizes, int n_in,
                              void* d_out, int out_size, void* d_ws, size_t ws_size,
                              hipStream_t stream)
{
    const float2* x1 = (const float2*)d_in[0];
    const float2* x2 = (const float2*)d_in[1];
    const float*  os = (const float*)d_in[2];
    float* out = (float*)d_out;

    // x: 8192/8 = 1024 col-groups / 256 threads -> 4 blocks; y: 8192 rows.
    dim3 block(256, 1, 1);
    dim3 grid((M_COLS / 8) / 256, N_ROWS, 1);
    ScaledRBFKernel_55052890800187_kernel<<<grid, block, 0, stream>>>(x1, x2, os, out);
}

// Round 4
// 57.639 us; speedup vs baseline: 1.8661x; 1.8661x over previous
//
#include <hip/hip_runtime.h>

// ScaledRBFKernel: out[i][j] = outputscale * exp(-2 * ||x1[i] - x2[j]||^2)
// x1: [8192,2] f32, x2: [8192,2] f32, out: [8192,8192] f32 (256 MiB -> write-BW bound)
// LENGTHSCALE = 0.5 -> 1/(2*l^2) = 2.0 (baked in)
// R4: 8 elem/thread with NORMAL stores. R3 lesson: nt stores bypass L2
// write-combining on CDNA4 -> 2.5x regression. Keep stores through L2.

#define N_ROWS 8192
#define M_COLS 8192

typedef float f32x4 __attribute__((ext_vector_type(4)));

__global__ __launch_bounds__(256) void ScaledRBFKernel_55052890800187_kernel(
    const float2* __restrict__ x1,   // [N,2] as float2
    const float2* __restrict__ x2,   // [M,2] as float2
    const float* __restrict__ oscale,
    float* __restrict__ out)
{
    const int i  = blockIdx.y;                              // row 0..8191
    const int j8 = blockIdx.x * blockDim.x + threadIdx.x;   // col-group of 8: 0..1023

    const float2 a = x1[i];
    const float  s = oscale[0];

    // 8 consecutive x2 points = 4 float4 loads (64 B/lane, L1/L2-resident)
    const f32x4* x2v = reinterpret_cast<const f32x4*>(x2);
    f32x4 p0 = x2v[j8 * 4 + 0];
    f32x4 p1 = x2v[j8 * 4 + 1];
    f32x4 p2 = x2v[j8 * 4 + 2];
    f32x4 p3 = x2v[j8 * 4 + 3];

    f32x4 r0, r1;
    {
        float dx = a.x - p0.x, dy = a.y - p0.y;
        r0.x = s * __expf(-2.0f * (dx * dx + dy * dy));
    }
    {
        float dx = a.x - p0.z, dy = a.y - p0.w;
        r0.y = s * __expf(-2.0f * (dx * dx + dy * dy));
    }
    {
        float dx = a.x - p1.x, dy = a.y - p1.y;
        r0.z = s * __expf(-2.0f * (dx * dx + dy * dy));
    }
    {
        float dx = a.x - p1.z, dy = a.y - p1.w;
        r0.w = s * __expf(-2.0f * (dx * dx + dy * dy));
    }
    {
        float dx = a.x - p2.x, dy = a.y - p2.y;
        r1.x = s * __expf(-2.0f * (dx * dx + dy * dy));
    }
    {
        float dx = a.x - p2.z, dy = a.y - p2.w;
        r1.y = s * __expf(-2.0f * (dx * dx + dy * dy));
    }
    {
        float dx = a.x - p3.x, dy = a.y - p3.y;
        r1.z = s * __expf(-2.0f * (dx * dx + dy * dy));
    }
    {
        float dx = a.x - p3.z, dy = a.y - p3.w;
        r1.w = s * __expf(-2.0f * (dx * dx + dy * dy));
    }

    f32x4* o = reinterpret_cast<f32x4*>(out) + (size_t)i * (M_COLS / 4) + (size_t)j8 * 2;
    o[0] = r0;
    o[1] = r1;
}

extern "C" void kernel_launch(void* const* d_in, const int* in_sizes, int n_in,
                              void* d_out, int out_size, void* d_ws, size_t ws_size,
                              hipStream_t stream)
{
    const float2* x1 = (const float2*)d_in[0];
    const float2* x2 = (const float2*)d_in[1];
    const float*  os = (const float*)d_in[2];
    float* out = (float*)d_out;

    // x: 8192/8 = 1024 col-groups / 256 threads -> 4 blocks; y: 8192 rows.
    dim3 block(256, 1, 1);
    dim3 grid((M_COLS / 8) / 256, N_ROWS, 1);
    ScaledRBFKernel_55052890800187_kernel<<<grid, block, 0, stream>>>(x1, x2, os, out);
}

// Round 5
// 44.141 us; speedup vs baseline: 2.4367x; 1.3058x over previous
//
#include <hip/hip_runtime.h>

// ScaledRBFKernel: out[i][j] = outputscale * exp(-2 * ||x1[i] - x2[j]||^2)
// x1: [8192,2] f32, x2: [8192,2] f32, out: [8192,8192] f32 (256 MiB -> write-BW bound)
// LENGTHSCALE = 0.5 -> 1/(2*l^2) = 2.0 (baked in)
// R5: 8 elem/thread, but each store instruction DENSE across the wave:
// thread owns col-group c4 and c4+1024 (two tiles 4 KB apart), so each
// global_store_dwordx4 covers contiguous 16 B/lane. R4 lesson: adjacent
// float4 pairs per thread -> 32 B lane stride per store -> 50% burst
// density -> +14 us. nt stores (R3): -2.5x, never again.

#define N_ROWS 8192
#define M_COLS 8192

typedef float f32x4 __attribute__((ext_vector_type(4)));

__global__ __launch_bounds__(256) void ScaledRBFKernel_55052890800187_kernel(
    const float2* __restrict__ x1,   // [N,2] as float2
    const float2* __restrict__ x2,   // [M,2] as float2
    const float* __restrict__ oscale,
    float* __restrict__ out)
{
    const int i  = blockIdx.y;                                  // row 0..8191
    const int c4 = blockIdx.x * blockDim.x + threadIdx.x;       // float4-col 0..1023 (tile A)
    // tile B is c4 + 1024 (float4-cols 1024..2047)

    const float2 a = x1[i];
    const float  s = oscale[0];

    const f32x4* x2v = reinterpret_cast<const f32x4*>(x2);      // 2 points per f32x4
    f32x4 pa0 = x2v[c4 * 2 + 0];
    f32x4 pa1 = x2v[c4 * 2 + 1];
    f32x4 pb0 = x2v[(c4 + 1024) * 2 + 0];
    f32x4 pb1 = x2v[(c4 + 1024) * 2 + 1];

    f32x4 ra, rb;
    {
        float dx = a.x - pa0.x, dy = a.y - pa0.y;
        ra.x = s * __expf(-2.0f * (dx * dx + dy * dy));
    }
    {
        float dx = a.x - pa0.z, dy = a.y - pa0.w;
        ra.y = s * __expf(-2.0f * (dx * dx + dy * dy));
    }
    {
        float dx = a.x - pa1.x, dy = a.y - pa1.y;
        ra.z = s * __expf(-2.0f * (dx * dx + dy * dy));
    }
    {
        float dx = a.x - pa1.z, dy = a.y - pa1.w;
        ra.w = s * __expf(-2.0f * (dx * dx + dy * dy));
    }
    {
        float dx = a.x - pb0.x, dy = a.y - pb0.y;
        rb.x = s * __expf(-2.0f * (dx * dx + dy * dy));
    }
    {
        float dx = a.x - pb0.z, dy = a.y - pb0.w;
        rb.y = s * __expf(-2.0f * (dx * dx + dy * dy));
    }
    {
        float dx = a.x - pb1.x, dy = a.y - pb1.y;
        rb.z = s * __expf(-2.0f * (dx * dx + dy * dy));
    }
    {
        float dx = a.x - pb1.z, dy = a.y - pb1.w;
        rb.w = s * __expf(-2.0f * (dx * dx + dy * dy));
    }

    f32x4* orow = reinterpret_cast<f32x4*>(out) + (size_t)i * (M_COLS / 4);
    orow[c4]        = ra;   // dense: 64 lanes x 16 B contiguous
    orow[c4 + 1024] = rb;   // dense second tile
}

extern "C" void kernel_launch(void* const* d_in, const int* in_sizes, int n_in,
                              void* d_out, int out_size, void* d_ws, size_t ws_size,
                              hipStream_t stream)
{
    const float2* x1 = (const float2*)d_in[0];
    const float2* x2 = (const float2*)d_in[1];
    const float*  os = (const float*)d_in[2];
    float* out = (float*)d_out;

    // x: 1024 float4-cols (tile A) / 256 threads -> 4 blocks; y: 8192 rows.
    dim3 block(256, 1, 1);
    dim3 grid(1024 / 256, N_ROWS, 1);
    ScaledRBFKernel_55052890800187_kernel<<<grid, block, 0, stream>>>(x1, x2, os, out);
}